// Round 16
// baseline (514.146 us; speedup 1.0000x reference)
//
#include <hip/hip_runtime.h>
#include <hip/hip_bf16.h>
#include <hip/hip_fp16.h>

// RWKV TimeMix, B=8 T=4096 C=1024 fp32.
// Round 16: r14 restored (best passing, 492.6us; r15's fusion regressed and is
// reverted) + ONE change: EPI=0 (fp32 out-GEMM) epilogue now LDS-staged for
// full-line coalesced stores (r14 counters showed 196MB writes for 134MB of
// data; same amplification the EPI=1 fp16 path already fixes).
// ws = 417,333,248 B (< proven 425,721,856).

#define BH 8
#define TT 4096
#define CC 1024
#define NCH 64
#define CHL (TT / NCH)

typedef _Float16       f16x8  __attribute__((ext_vector_type(8)));
typedef float          f32x4  __attribute__((ext_vector_type(4)));
typedef unsigned short ushort_t;

__device__ __forceinline__ ushort_t f2h_u(float f) {
  return __half_as_ushort(__float2half(f));          // RN
}

#define GLOAD_LDS16(g, l)                                                     \
  __builtin_amdgcn_global_load_lds(                                           \
      (const __attribute__((address_space(1))) unsigned int*)(g),             \
      (__attribute__((address_space(3))) unsigned int*)(l), 16, 0, 0)

#define BARRIER() do { asm volatile("" ::: "memory");                        \
                       __builtin_amdgcn_s_barrier();                          \
                       asm volatile("" ::: "memory"); } while (0)

#define LGKM0() do { asm volatile("s_waitcnt lgkmcnt(0)" ::: "memory");      \
                     __builtin_amdgcn_sched_barrier(0); } while (0)

#define WAITV(n) do { asm volatile("s_waitcnt vmcnt(" #n ")" ::: "memory");  \
                      __builtin_amdgcn_sched_barrier(0); } while (0)

// ---- W matrices -> fp16 (4 bufs of CC*CC) ----
__global__ __launch_bounds__(256)
void split_w(const float* __restrict__ W0, const float* __restrict__ W1,
             const float* __restrict__ W2, const float* __restrict__ W3,
             ushort_t* __restrict__ out)
{
  int idx = blockIdx.x * 256 + threadIdx.x;
  int w = idx >> 20;
  int e = idx & (CC * CC - 1);
  const float* src = (w == 0) ? W0 : (w == 1) ? W1 : (w == 2) ? W2 : W3;
  out[(size_t)w * CC * CC + e] = f2h_u(src[e]);
}

// ---- fused time-shift lerp: read x once, write xk/xv/xr fp16 ----
__global__ __launch_bounds__(256)
void lerp3(const float* __restrict__ x,
           const float* __restrict__ mk, const float* __restrict__ mv,
           const float* __restrict__ mr,
           ushort_t* __restrict__ xk, ushort_t* __restrict__ xv,
           ushort_t* __restrict__ xr)
{
  const int idx = blockIdx.x * 256 + threadIdx.x;   // one float4 per thread
  const int m = idx >> 8;
  const int c = (idx & 255) * 4;
  const size_t e = (size_t)m * CC + c;
  float4 cu = *(const float4*)(x + e);
  float4 pv = make_float4(0.f, 0.f, 0.f, 0.f);
  if ((m & (TT - 1)) != 0) pv = *(const float4*)(x + e - CC);

  const float* mixes[3] = {mk, mv, mr};
  ushort_t* outs[3] = {xk, xv, xr};
  #pragma unroll
  for (int z = 0; z < 3; ++z) {
    float4 mx = *(const float4*)(mixes[z] + c);
    float a0 = pv.x + mx.x * (cu.x - pv.x);
    float a1 = pv.y + mx.y * (cu.y - pv.y);
    float a2 = pv.z + mx.z * (cu.z - pv.z);
    float a3 = pv.w + mx.w * (cu.w - pv.w);
    *(ushort4*)(outs[z] + e) = make_ushort4(f2h_u(a0), f2h_u(a1), f2h_u(a2), f2h_u(a3));
  }
}

// ---- fp16 GEMM, K=1024, z-batched; 256x256 tile, BK=64, 4-phase (r14) ----
// 512 thr = 8 waves (2M x 4N), per-wave 128x64 (8x4 frags of 16x16x32).
// LDS: 2 bufs x 4 regions (A-ks0, B-ks0, A-ks1, B-ks1), each [256][32],
// swizzle q^((row>>1)&3) (0 conflicts measured r2..r14).
// EPI=1: stride-280 LDS-staged fp16 epilogue (r14-proven).
// EPI=0: stride-260 LDS-staged fp32 epilogue (NEW: full-line stores).
template<int EPI>
__global__ __launch_bounds__(512, 2)
void gemm_f16(const ushort_t* __restrict__ Ab, const ushort_t* __restrict__ Bb,
              void* __restrict__ Dv)
{
  constexpr int NS = 16;   // K-steps of 64 over K=1024
  const size_t nbt = (size_t)BH * TT * CC;

  __shared__ __align__(16) ushort_t lds[2][4][8192];   // [buf][region][256*32]

  const int tid  = threadIdx.x;
  const int wave = tid >> 6, lane = tid & 63;
  const int wm = wave & 1, wn = wave >> 1;
  const int lr = lane & 15, kg = lane >> 4;

  const int z = blockIdx.z;
  const ushort_t* Ah = Ab + (size_t)z * nbt;
  const ushort_t* Bh = Bb + (size_t)z * CC * CC;

  // XCD-aware bijective swizzle (nwg=512, 512%8==0)
  const int bid = blockIdx.x;
  const int swz = (bid & 7) * 64 + (bid >> 3);
  const int m0 = (swz >> 2) * 256;     // 128 m-blocks
  const int n0 = (swz & 3) * 256;      // 4 n-blocks

  f32x4 acc[8][4] = {};

  // stage one 16KiB region: part 0=A-ks0 1=B-ks0 2=A-ks1 3=B-ks1
  auto stage = [&](int s, int part) {
    if (s >= NS) return;
    const int kk = s * 64 + (part >> 1) * 32;
    const ushort_t* g0 = (part & 1) ? Bh : Ah;
    const int r0 = (part & 1) ? n0 : m0;
    #pragma unroll
    for (int c = 0; c < 2; ++c) {
      const int row = c * 128 + (tid >> 2);
      const int q   = (tid & 3) ^ ((row >> 1) & 3);
      const ushort_t* src = g0 + (size_t)(r0 + row) * CC + kk + q * 8;
      ushort_t* dst = &lds[s & 1][part][c * 4096 + wave * 512];  // wave-uniform
      GLOAD_LDS16(src, dst);
    }
  };
  auto rdA = [&](int b, int ks, int fm) -> f16x8 {
    const int row = wm * 128 + fm * 16 + lr;
    const int q   = kg ^ ((row >> 1) & 3);
    return *(const f16x8*)&lds[b][ks * 2][row * 32 + q * 8];
  };
  auto rdB = [&](int b, int ks, int fn) -> f16x8 {
    const int row = wn * 64 + fn * 16 + lr;
    const int q   = kg ^ ((row >> 1) & 3);
    return *(const f16x8*)&lds[b][ks * 2 + 1][row * 32 + q * 8];
  };

  // ---- prologue: [0,A0][0,B0][0,A1][0,B1][1,A0][1,B0]; oldest 2 regions landed
  stage(0, 0); stage(0, 1); stage(0, 2); stage(0, 3);
  stage(1, 0); stage(1, 1);
  WAITV(8);
  BARRIER();

  for (int s = 0; s < NS; ++s) {
    const int b = s & 1;
    f16x8 bfr[4], afr[4];

    // ---- P1: frags(B ks0, A m0-3 ks0); stage (s+1, A-ks1)
    #pragma unroll
    for (int fn = 0; fn < 4; ++fn) bfr[fn] = rdB(b, 0, fn);
    #pragma unroll
    for (int i = 0; i < 4; ++i) afr[i] = rdA(b, 0, i);
    stage(s + 1, 2);
    BARRIER();
    LGKM0();
    __builtin_amdgcn_s_setprio(1);
    #pragma unroll
    for (int i = 0; i < 4; ++i)
      #pragma unroll
      for (int fn = 0; fn < 4; ++fn)
        acc[i][fn] = __builtin_amdgcn_mfma_f32_16x16x32_f16(afr[i], bfr[fn], acc[i][fn], 0, 0, 0);
    __builtin_amdgcn_s_setprio(0);
    BARRIER();

    // ---- P2: frags(A m4-7 ks0); stage (s+1, B-ks1); wait + barrier
    #pragma unroll
    for (int i = 0; i < 4; ++i) afr[i] = rdA(b, 0, 4 + i);
    stage(s + 1, 3);
    BARRIER();
    LGKM0();
    __builtin_amdgcn_s_setprio(1);
    #pragma unroll
    for (int i = 0; i < 4; ++i)
      #pragma unroll
      for (int fn = 0; fn < 4; ++fn)
        acc[4 + i][fn] = __builtin_amdgcn_mfma_f32_16x16x32_f16(afr[i], bfr[fn], acc[4 + i][fn], 0, 0, 0);
    __builtin_amdgcn_s_setprio(0);
    if (s < NS - 1) { WAITV(8); } else { WAITV(0); }
    BARRIER();

    // ---- P3: frags(B ks1, A m0-3 ks1); stage (s+2, A-ks0)
    #pragma unroll
    for (int fn = 0; fn < 4; ++fn) bfr[fn] = rdB(b, 1, fn);
    #pragma unroll
    for (int i = 0; i < 4; ++i) afr[i] = rdA(b, 1, i);
    stage(s + 2, 0);
    BARRIER();
    LGKM0();
    __builtin_amdgcn_s_setprio(1);
    #pragma unroll
    for (int i = 0; i < 4; ++i)
      #pragma unroll
      for (int fn = 0; fn < 4; ++fn)
        acc[i][fn] = __builtin_amdgcn_mfma_f32_16x16x32_f16(afr[i], bfr[fn], acc[i][fn], 0, 0, 0);
    __builtin_amdgcn_s_setprio(0);
    BARRIER();

    // ---- P4: frags(A m4-7 ks1); stage (s+2, B-ks0); wait + barrier
    #pragma unroll
    for (int i = 0; i < 4; ++i) afr[i] = rdA(b, 1, 4 + i);
    stage(s + 2, 1);
    BARRIER();
    LGKM0();
    __builtin_amdgcn_s_setprio(1);
    #pragma unroll
    for (int i = 0; i < 4; ++i)
      #pragma unroll
      for (int fn = 0; fn < 4; ++fn)
        acc[4 + i][fn] = __builtin_amdgcn_mfma_f32_16x16x32_f16(afr[i], bfr[fn], acc[4 + i][fn], 0, 0, 0);
    __builtin_amdgcn_s_setprio(0);
    if (s < NS - 2)       { WAITV(8); }
    else if (s == NS - 2) { WAITV(4); }
    BARRIER();
  }

  if (EPI == 0) {
    // NEW: LDS-staged coalesced fp32 epilogue. 8 slices (fm) of 32 rows x 256
    // f32, row stride 260 (write phase: 2 lanes/bank uniform = free; read-back
    // volume-limited). Read-back: thread -> 64B (4x float4), rows of 1KiB
    // fully covered by 16 threads -> full-line stores.
    float* Df = (float*)Dv;
    float* epf = (float*)&lds[0][0][0];         // 32*260 f32 = 33,280 B
    const int rowl = tid >> 4;                  // 0..31
    const int ck   = tid & 15;                  // 16-f32 chunk index
    #pragma unroll
    for (int sl = 0; sl < 8; ++sl) {            // static acc[sl]
      __syncthreads();                          // prev slice reads done
      #pragma unroll
      for (int fn = 0; fn < 4; ++fn)
        #pragma unroll
        for (int r = 0; r < 4; ++r)
          epf[(wm * 16 + kg * 4 + r) * 260 + wn * 64 + fn * 16 + lr] =
              acc[sl][fn][r];
      __syncthreads();                          // writes visible
      const int grow = m0 + (rowl >> 4) * 128 + sl * 16 + (rowl & 15);
      float* dst = Df + (size_t)grow * CC + n0 + ck * 16;
      const float* srcl = &epf[rowl * 260 + ck * 16];
      #pragma unroll
      for (int j = 0; j < 4; ++j)
        *(float4*)(dst + j * 4) = *(const float4*)(srcl + j * 4);
    }
  } else {
    // LDS-staged coalesced fp16 epilogue (r14-proven): 8 slices of 32x256,
    // row stride 280 halfs.
    __half* Dh = (__half*)Dv + (size_t)z * nbt;
    __half* ep = (__half*)&lds[0][0][0];        // 32*280 halfs = 17.5 KiB
    const int rowl = tid >> 4;                  // 0..31
    const int ck   = tid & 15;                  // 16-half chunk index
    #pragma unroll
    for (int sl = 0; sl < 8; ++sl) {            // static acc[sl]
      __syncthreads();                          // prev slice reads done
      #pragma unroll
      for (int fn = 0; fn < 4; ++fn)
        #pragma unroll
        for (int r = 0; r < 4; ++r)
          ep[(wm * 16 + kg * 4 + r) * 280 + wn * 64 + fn * 16 + lr] =
              __float2half(acc[sl][fn][r]);
      __syncthreads();                          // writes visible
      uint4 v0 = *(const uint4*)&ep[rowl * 280 + ck * 16];
      uint4 v1 = *(const uint4*)&ep[rowl * 280 + ck * 16 + 8];
      const int grow = m0 + (rowl >> 4) * 128 + sl * 16 + (rowl & 15);
      __half* dst = Dh + (size_t)grow * CC + n0 + ck * 16;
      *(uint4*)dst = v0;
      *(uint4*)(dst + 8) = v1;
    }
  }
}

// ---- WKV chunked scan (fp16 k,v,r) ----
__global__ __launch_bounds__(256)
void wkv_phase_a(const __half* __restrict__ kb, const __half* __restrict__ vb,
                 const float* __restrict__ decay,
                 float* __restrict__ SA, float* __restrict__ SB, float* __restrict__ SP)
{
  const int idx = blockIdx.x * 256 + threadIdx.x;
  const int c  = idx & (CC - 1);
  const int bc = idx >> 10;
  const int ch = bc & (NCH - 1);
  const int b  = bc >> 6;
  const float w = -__expf(decay[c]);
  float aa = 0.f, bb = 0.f, pp = -1e38f;
  size_t base = ((size_t)b * TT + (size_t)ch * CHL) * CC + c;
  #pragma unroll 4
  for (int t = 0; t < CHL; ++t) {
    const float kt = __half2float(kb[base]);
    const float vt = __half2float(vb[base]);
    const float q2 = fmaxf(pp + w, kt);
    const float f1 = __expf(pp + w - q2);
    const float f2 = __expf(kt - q2);
    aa = f1 * aa + f2 * vt; bb = f1 * bb + f2; pp = q2;
    base += CC;
  }
  SA[idx] = aa; SB[idx] = bb; SP[idx] = pp;
}

__global__ __launch_bounds__(256)
void wkv_combine(float* __restrict__ SA, float* __restrict__ SB, float* __restrict__ SP,
                 const float* __restrict__ decay)
{
  const int idx = blockIdx.x * 256 + threadIdx.x;
  const int c = idx & (CC - 1);
  const int b = idx >> 10;
  const float w  = -__expf(decay[c]);
  const float wL = w * (float)CHL;
  float aa = 0.f, bb = 0.f, pp = -1e38f;
  for (int ch = 0; ch < NCH; ++ch) {
    const size_t s = ((size_t)b * NCH + ch) * CC + c;
    const float la = SA[s], lb = SB[s], lp = SP[s];
    SA[s] = aa; SB[s] = bb; SP[s] = pp;
    const float pw = pp + wL;
    const float q  = fmaxf(pw, lp);
    const float e1 = __expf(pw - q);
    const float e2 = __expf(lp - q);
    aa = e1 * aa + e2 * la; bb = e1 * bb + e2 * lb; pp = q;
  }
}

__global__ __launch_bounds__(256)
void wkv_phase_c(const __half* __restrict__ kb, const __half* __restrict__ vb,
                 const __half* __restrict__ rb, const float* __restrict__ decay,
                 const float* __restrict__ first,
                 const float* __restrict__ SA, const float* __restrict__ SB,
                 const float* __restrict__ SP,
                 ushort_t* __restrict__ yh)
{
  const int idx = blockIdx.x * 256 + threadIdx.x;
  const int c  = idx & (CC - 1);
  const int bc = idx >> 10;
  const int ch = bc & (NCH - 1);
  const int b  = bc >> 6;
  const float w = -__expf(decay[c]);
  const float u = first[c];
  float aa = SA[idx], bb = SB[idx], pp = SP[idx];
  size_t base = ((size_t)b * TT + (size_t)ch * CHL) * CC + c;
  #pragma unroll 4
  for (int t = 0; t < CHL; ++t) {
    const float kt = __half2float(kb[base]);
    const float vt = __half2float(vb[base]);
    const float rt = __half2float(rb[base]);
    const float q  = fmaxf(pp, u + kt);
    const float e1 = __expf(pp - q);
    const float e2 = __expf(u + kt - q);
    const float yv = (e1 * aa + e2 * vt) / (e1 * bb + e2);
    const float sr = 1.f / (1.f + __expf(-rt));
    yh[base] = f2h_u(sr * yv);
    const float q2 = fmaxf(pp + w, kt);
    const float f1 = __expf(pp + w - q2);
    const float f2 = __expf(kt - q2);
    aa = f1 * aa + f2 * vt; bb = f1 * bb + f2; pp = q2;
    base += CC;
  }
}

extern "C" void kernel_launch(void* const* d_in, const int* in_sizes, int n_in,
                              void* d_out, int out_size, void* d_ws, size_t ws_size,
                              hipStream_t stream) {
  const float* x     = (const float*)d_in[0];
  const float* decay = (const float*)d_in[1];
  const float* first = (const float*)d_in[2];
  const float* mk    = (const float*)d_in[3];
  const float* mv    = (const float*)d_in[4];
  const float* mr    = (const float*)d_in[5];
  const float* Wk    = (const float*)d_in[6];
  const float* Wv    = (const float*)d_in[7];
  const float* Wr    = (const float*)d_in[8];
  const float* Wo    = (const float*)d_in[9];
  float* out = (float*)d_out;

  const size_t nbt = (size_t)BH * TT * CC;       // 33,554,432
  const size_t WS  = (size_t)CC * CC;            // 1,048,576
  // ws layout (bytes), total 417,333,248 < proven 425,721,856:
  char* p = (char*)d_ws;
  ushort_t* xk   = (ushort_t*)(p);                               //  67,108,864 (-> y)
  ushort_t* xv   = (ushort_t*)(p +  67108864);                   //  67,108,864
  ushort_t* xr   = (ushort_t*)(p + 134217728);                   //  67,108,864
  __half*   kbuf = (__half*)  (p + 201326592);                   //  67,108,864
  __half*   vbuf = (__half*)  (p + 268435456);                   //  67,108,864
  __half*   rbuf = (__half*)  (p + 335544320);                   //  67,108,864
  ushort_t* Wsp  = (ushort_t*)(p + 402653184);                   //   8,388,608 (4 bufs)
  float*    SA   = (float*)   (p + 411041792);                   //   2,097,152
  float*    SB   = (float*)   (p + 413138944);
  float*    SP   = (float*)   (p + 415236096);

  dim3 blk(256);
  const dim3 gblk(512);
  const unsigned lerpg = (unsigned)(nbt / 4 / 256);

  split_w<<<dim3(4 * CC * CC / 256), blk, 0, stream>>>(Wk, Wv, Wr, Wo, Wsp);
  lerp3<<<dim3(lerpg), blk, 0, stream>>>(x, mk, mv, mr, xk, xv, xr);

  // k,v,r GEMMs in one z-batched dispatch
  gemm_f16<1><<<dim3(512, 1, 3), gblk, 0, stream>>>(xk, Wsp, (void*)kbuf);

  const int nscan = BH * NCH * CC;
  wkv_phase_a<<<dim3(nscan / 256), blk, 0, stream>>>(kbuf, vbuf, decay, SA, SB, SP);
  wkv_combine<<<dim3(BH * CC / 256), blk, 0, stream>>>(SA, SB, SP, decay);
  wkv_phase_c<<<dim3(nscan / 256), blk, 0, stream>>>(kbuf, vbuf, rbuf, decay, first,
                                                     SA, SB, SP, xk);

  gemm_f16<0><<<dim3(512, 1, 1), gblk, 0, stream>>>(xk, Wsp + 3 * WS, (void*)out);
}

// Round 17
// 491.076 us; speedup vs baseline: 1.0470x; 1.0470x over previous
//
#include <hip/hip_runtime.h>
#include <hip/hip_bf16.h>
#include <hip/hip_fp16.h>

// RWKV TimeMix, B=8 T=4096 C=1024 fp32.
// Round 17: r14 restored verbatim (best passing, 492.6us). r15 (fused3) and
// r16 (fp32 epilogue staging) both regressed and are reverted. This is the
// lock-in of the best-known configuration:
//   split_w -> lerp3 -> z-batched 4-phase fp16 GEMM (k/v/r) -> 3-phase
//   chunked WKV scan -> fp16 out-GEMM with fp32 direct stores.
// ws = 417,333,248 B (< proven 425,721,856).

#define BH 8
#define TT 4096
#define CC 1024
#define NCH 64
#define CHL (TT / NCH)

typedef _Float16       f16x8  __attribute__((ext_vector_type(8)));
typedef float          f32x4  __attribute__((ext_vector_type(4)));
typedef unsigned short ushort_t;

__device__ __forceinline__ ushort_t f2h_u(float f) {
  return __half_as_ushort(__float2half(f));          // RN
}

#define GLOAD_LDS16(g, l)                                                     \
  __builtin_amdgcn_global_load_lds(                                           \
      (const __attribute__((address_space(1))) unsigned int*)(g),             \
      (__attribute__((address_space(3))) unsigned int*)(l), 16, 0, 0)

#define BARRIER() do { asm volatile("" ::: "memory");                        \
                       __builtin_amdgcn_s_barrier();                          \
                       asm volatile("" ::: "memory"); } while (0)

#define LGKM0() do { asm volatile("s_waitcnt lgkmcnt(0)" ::: "memory");      \
                     __builtin_amdgcn_sched_barrier(0); } while (0)

#define WAITV(n) do { asm volatile("s_waitcnt vmcnt(" #n ")" ::: "memory");  \
                      __builtin_amdgcn_sched_barrier(0); } while (0)

// ---- W matrices -> fp16 (4 bufs of CC*CC) ----
__global__ __launch_bounds__(256)
void split_w(const float* __restrict__ W0, const float* __restrict__ W1,
             const float* __restrict__ W2, const float* __restrict__ W3,
             ushort_t* __restrict__ out)
{
  int idx = blockIdx.x * 256 + threadIdx.x;
  int w = idx >> 20;
  int e = idx & (CC * CC - 1);
  const float* src = (w == 0) ? W0 : (w == 1) ? W1 : (w == 2) ? W2 : W3;
  out[(size_t)w * CC * CC + e] = f2h_u(src[e]);
}

// ---- fused time-shift lerp: read x once, write xk/xv/xr fp16 ----
__global__ __launch_bounds__(256)
void lerp3(const float* __restrict__ x,
           const float* __restrict__ mk, const float* __restrict__ mv,
           const float* __restrict__ mr,
           ushort_t* __restrict__ xk, ushort_t* __restrict__ xv,
           ushort_t* __restrict__ xr)
{
  const int idx = blockIdx.x * 256 + threadIdx.x;   // one float4 per thread
  const int m = idx >> 8;
  const int c = (idx & 255) * 4;
  const size_t e = (size_t)m * CC + c;
  float4 cu = *(const float4*)(x + e);
  float4 pv = make_float4(0.f, 0.f, 0.f, 0.f);
  if ((m & (TT - 1)) != 0) pv = *(const float4*)(x + e - CC);

  const float* mixes[3] = {mk, mv, mr};
  ushort_t* outs[3] = {xk, xv, xr};
  #pragma unroll
  for (int z = 0; z < 3; ++z) {
    float4 mx = *(const float4*)(mixes[z] + c);
    float a0 = pv.x + mx.x * (cu.x - pv.x);
    float a1 = pv.y + mx.y * (cu.y - pv.y);
    float a2 = pv.z + mx.z * (cu.z - pv.z);
    float a3 = pv.w + mx.w * (cu.w - pv.w);
    *(ushort4*)(outs[z] + e) = make_ushort4(f2h_u(a0), f2h_u(a1), f2h_u(a2), f2h_u(a3));
  }
}

// ---- fp16 GEMM, K=1024, z-batched; 256x256 tile, BK=64, 4-phase ----
// 512 thr = 8 waves (2M x 4N), per-wave 128x64 (8x4 frags of 16x16x32).
// LDS: 2 bufs x 4 regions (A-ks0, B-ks0, A-ks1, B-ks1), each [256][32],
// swizzle q^((row>>1)&3) (0 conflicts measured r2..r16).
// EPI=1: stride-280 LDS-staged fp16 epilogue. EPI=0: direct fp32 stores
// (64B full-segment chunks, 1x write amplification per r8 counters).
template<int EPI>
__global__ __launch_bounds__(512, 2)
void gemm_f16(const ushort_t* __restrict__ Ab, const ushort_t* __restrict__ Bb,
              void* __restrict__ Dv)
{
  constexpr int NS = 16;   // K-steps of 64 over K=1024
  const size_t nbt = (size_t)BH * TT * CC;

  __shared__ __align__(16) ushort_t lds[2][4][8192];   // [buf][region][256*32]

  const int tid  = threadIdx.x;
  const int wave = tid >> 6, lane = tid & 63;
  const int wm = wave & 1, wn = wave >> 1;
  const int lr = lane & 15, kg = lane >> 4;

  const int z = blockIdx.z;
  const ushort_t* Ah = Ab + (size_t)z * nbt;
  const ushort_t* Bh = Bb + (size_t)z * CC * CC;

  // XCD-aware bijective swizzle (nwg=512, 512%8==0)
  const int bid = blockIdx.x;
  const int swz = (bid & 7) * 64 + (bid >> 3);
  const int m0 = (swz >> 2) * 256;     // 128 m-blocks
  const int n0 = (swz & 3) * 256;      // 4 n-blocks

  f32x4 acc[8][4] = {};

  // stage one 16KiB region: part 0=A-ks0 1=B-ks0 2=A-ks1 3=B-ks1
  auto stage = [&](int s, int part) {
    if (s >= NS) return;
    const int kk = s * 64 + (part >> 1) * 32;
    const ushort_t* g0 = (part & 1) ? Bh : Ah;
    const int r0 = (part & 1) ? n0 : m0;
    #pragma unroll
    for (int c = 0; c < 2; ++c) {
      const int row = c * 128 + (tid >> 2);
      const int q   = (tid & 3) ^ ((row >> 1) & 3);
      const ushort_t* src = g0 + (size_t)(r0 + row) * CC + kk + q * 8;
      ushort_t* dst = &lds[s & 1][part][c * 4096 + wave * 512];  // wave-uniform
      GLOAD_LDS16(src, dst);
    }
  };
  auto rdA = [&](int b, int ks, int fm) -> f16x8 {
    const int row = wm * 128 + fm * 16 + lr;
    const int q   = kg ^ ((row >> 1) & 3);
    return *(const f16x8*)&lds[b][ks * 2][row * 32 + q * 8];
  };
  auto rdB = [&](int b, int ks, int fn) -> f16x8 {
    const int row = wn * 64 + fn * 16 + lr;
    const int q   = kg ^ ((row >> 1) & 3);
    return *(const f16x8*)&lds[b][ks * 2 + 1][row * 32 + q * 8];
  };

  // ---- prologue: [0,A0][0,B0][0,A1][0,B1][1,A0][1,B0]; oldest 2 regions landed
  stage(0, 0); stage(0, 1); stage(0, 2); stage(0, 3);
  stage(1, 0); stage(1, 1);
  WAITV(8);
  BARRIER();

  for (int s = 0; s < NS; ++s) {
    const int b = s & 1;
    f16x8 bfr[4], afr[4];

    // ---- P1: frags(B ks0, A m0-3 ks0); stage (s+1, A-ks1)
    #pragma unroll
    for (int fn = 0; fn < 4; ++fn) bfr[fn] = rdB(b, 0, fn);
    #pragma unroll
    for (int i = 0; i < 4; ++i) afr[i] = rdA(b, 0, i);
    stage(s + 1, 2);
    BARRIER();
    LGKM0();
    __builtin_amdgcn_s_setprio(1);
    #pragma unroll
    for (int i = 0; i < 4; ++i)
      #pragma unroll
      for (int fn = 0; fn < 4; ++fn)
        acc[i][fn] = __builtin_amdgcn_mfma_f32_16x16x32_f16(afr[i], bfr[fn], acc[i][fn], 0, 0, 0);
    __builtin_amdgcn_s_setprio(0);
    BARRIER();

    // ---- P2: frags(A m4-7 ks0); stage (s+1, B-ks1); wait + barrier
    #pragma unroll
    for (int i = 0; i < 4; ++i) afr[i] = rdA(b, 0, 4 + i);
    stage(s + 1, 3);
    BARRIER();
    LGKM0();
    __builtin_amdgcn_s_setprio(1);
    #pragma unroll
    for (int i = 0; i < 4; ++i)
      #pragma unroll
      for (int fn = 0; fn < 4; ++fn)
        acc[4 + i][fn] = __builtin_amdgcn_mfma_f32_16x16x32_f16(afr[i], bfr[fn], acc[4 + i][fn], 0, 0, 0);
    __builtin_amdgcn_s_setprio(0);
    if (s < NS - 1) { WAITV(8); } else { WAITV(0); }
    BARRIER();

    // ---- P3: frags(B ks1, A m0-3 ks1); stage (s+2, A-ks0)
    #pragma unroll
    for (int fn = 0; fn < 4; ++fn) bfr[fn] = rdB(b, 1, fn);
    #pragma unroll
    for (int i = 0; i < 4; ++i) afr[i] = rdA(b, 1, i);
    stage(s + 2, 0);
    BARRIER();
    LGKM0();
    __builtin_amdgcn_s_setprio(1);
    #pragma unroll
    for (int i = 0; i < 4; ++i)
      #pragma unroll
      for (int fn = 0; fn < 4; ++fn)
        acc[i][fn] = __builtin_amdgcn_mfma_f32_16x16x32_f16(afr[i], bfr[fn], acc[i][fn], 0, 0, 0);
    __builtin_amdgcn_s_setprio(0);
    BARRIER();

    // ---- P4: frags(A m4-7 ks1); stage (s+2, B-ks0); wait + barrier
    #pragma unroll
    for (int i = 0; i < 4; ++i) afr[i] = rdA(b, 1, 4 + i);
    stage(s + 2, 1);
    BARRIER();
    LGKM0();
    __builtin_amdgcn_s_setprio(1);
    #pragma unroll
    for (int i = 0; i < 4; ++i)
      #pragma unroll
      for (int fn = 0; fn < 4; ++fn)
        acc[4 + i][fn] = __builtin_amdgcn_mfma_f32_16x16x32_f16(afr[i], bfr[fn], acc[4 + i][fn], 0, 0, 0);
    __builtin_amdgcn_s_setprio(0);
    if (s < NS - 2)       { WAITV(8); }
    else if (s == NS - 2) { WAITV(4); }
    BARRIER();
  }

  if (EPI == 0) {
    // direct fp32 stores (16 lanes x 4B = 64B full segments; 1x amplification)
    float* Df = (float*)Dv;
    #pragma unroll
    for (int fm = 0; fm < 8; ++fm)
      #pragma unroll
      for (int fn = 0; fn < 4; ++fn) {
        const int col  = n0 + wn * 64 + fn * 16 + lr;
        const int rowb = m0 + wm * 128 + fm * 16 + kg * 4;
        #pragma unroll
        for (int r = 0; r < 4; ++r)
          Df[(size_t)(rowb + r) * CC + col] = acc[fm][fn][r];
      }
  } else {
    // LDS-staged coalesced fp16 epilogue: 8 slices of 32x256, row stride 280.
    __half* Dh = (__half*)Dv + (size_t)z * nbt;
    __half* ep = (__half*)&lds[0][0][0];        // 32*280 halfs = 17.5 KiB
    const int rowl = tid >> 4;                  // 0..31
    const int ck   = tid & 15;                  // 16-half chunk index
    #pragma unroll
    for (int sl = 0; sl < 8; ++sl) {            // static acc[sl]
      __syncthreads();                          // prev slice reads done
      #pragma unroll
      for (int fn = 0; fn < 4; ++fn)
        #pragma unroll
        for (int r = 0; r < 4; ++r)
          ep[(wm * 16 + kg * 4 + r) * 280 + wn * 64 + fn * 16 + lr] =
              __float2half(acc[sl][fn][r]);
      __syncthreads();                          // writes visible
      uint4 v0 = *(const uint4*)&ep[rowl * 280 + ck * 16];
      uint4 v1 = *(const uint4*)&ep[rowl * 280 + ck * 16 + 8];
      const int grow = m0 + (rowl >> 4) * 128 + sl * 16 + (rowl & 15);
      __half* dst = Dh + (size_t)grow * CC + n0 + ck * 16;
      *(uint4*)dst = v0;
      *(uint4*)(dst + 8) = v1;
    }
  }
}

// ---- WKV chunked scan (fp16 k,v,r) ----
__global__ __launch_bounds__(256)
void wkv_phase_a(const __half* __restrict__ kb, const __half* __restrict__ vb,
                 const float* __restrict__ decay,
                 float* __restrict__ SA, float* __restrict__ SB, float* __restrict__ SP)
{
  const int idx = blockIdx.x * 256 + threadIdx.x;
  const int c  = idx & (CC - 1);
  const int bc = idx >> 10;
  const int ch = bc & (NCH - 1);
  const int b  = bc >> 6;
  const float w = -__expf(decay[c]);
  float aa = 0.f, bb = 0.f, pp = -1e38f;
  size_t base = ((size_t)b * TT + (size_t)ch * CHL) * CC + c;
  #pragma unroll 4
  for (int t = 0; t < CHL; ++t) {
    const float kt = __half2float(kb[base]);
    const float vt = __half2float(vb[base]);
    const float q2 = fmaxf(pp + w, kt);
    const float f1 = __expf(pp + w - q2);
    const float f2 = __expf(kt - q2);
    aa = f1 * aa + f2 * vt; bb = f1 * bb + f2; pp = q2;
    base += CC;
  }
  SA[idx] = aa; SB[idx] = bb; SP[idx] = pp;
}

__global__ __launch_bounds__(256)
void wkv_combine(float* __restrict__ SA, float* __restrict__ SB, float* __restrict__ SP,
                 const float* __restrict__ decay)
{
  const int idx = blockIdx.x * 256 + threadIdx.x;
  const int c = idx & (CC - 1);
  const int b = idx >> 10;
  const float w  = -__expf(decay[c]);
  const float wL = w * (float)CHL;
  float aa = 0.f, bb = 0.f, pp = -1e38f;
  for (int ch = 0; ch < NCH; ++ch) {
    const size_t s = ((size_t)b * NCH + ch) * CC + c;
    const float la = SA[s], lb = SB[s], lp = SP[s];
    SA[s] = aa; SB[s] = bb; SP[s] = pp;
    const float pw = pp + wL;
    const float q  = fmaxf(pw, lp);
    const float e1 = __expf(pw - q);
    const float e2 = __expf(lp - q);
    aa = e1 * aa + e2 * la; bb = e1 * bb + e2 * lb; pp = q;
  }
}

__global__ __launch_bounds__(256)
void wkv_phase_c(const __half* __restrict__ kb, const __half* __restrict__ vb,
                 const __half* __restrict__ rb, const float* __restrict__ decay,
                 const float* __restrict__ first,
                 const float* __restrict__ SA, const float* __restrict__ SB,
                 const float* __restrict__ SP,
                 ushort_t* __restrict__ yh)
{
  const int idx = blockIdx.x * 256 + threadIdx.x;
  const int c  = idx & (CC - 1);
  const int bc = idx >> 10;
  const int ch = bc & (NCH - 1);
  const int b  = bc >> 6;
  const float w = -__expf(decay[c]);
  const float u = first[c];
  float aa = SA[idx], bb = SB[idx], pp = SP[idx];
  size_t base = ((size_t)b * TT + (size_t)ch * CHL) * CC + c;
  #pragma unroll 4
  for (int t = 0; t < CHL; ++t) {
    const float kt = __half2float(kb[base]);
    const float vt = __half2float(vb[base]);
    const float rt = __half2float(rb[base]);
    const float q  = fmaxf(pp, u + kt);
    const float e1 = __expf(pp - q);
    const float e2 = __expf(u + kt - q);
    const float yv = (e1 * aa + e2 * vt) / (e1 * bb + e2);
    const float sr = 1.f / (1.f + __expf(-rt));
    yh[base] = f2h_u(sr * yv);
    const float q2 = fmaxf(pp + w, kt);
    const float f1 = __expf(pp + w - q2);
    const float f2 = __expf(kt - q2);
    aa = f1 * aa + f2 * vt; bb = f1 * bb + f2; pp = q2;
    base += CC;
  }
}

extern "C" void kernel_launch(void* const* d_in, const int* in_sizes, int n_in,
                              void* d_out, int out_size, void* d_ws, size_t ws_size,
                              hipStream_t stream) {
  const float* x     = (const float*)d_in[0];
  const float* decay = (const float*)d_in[1];
  const float* first = (const float*)d_in[2];
  const float* mk    = (const float*)d_in[3];
  const float* mv    = (const float*)d_in[4];
  const float* mr    = (const float*)d_in[5];
  const float* Wk    = (const float*)d_in[6];
  const float* Wv    = (const float*)d_in[7];
  const float* Wr    = (const float*)d_in[8];
  const float* Wo    = (const float*)d_in[9];
  float* out = (float*)d_out;

  const size_t nbt = (size_t)BH * TT * CC;       // 33,554,432
  const size_t WS  = (size_t)CC * CC;            // 1,048,576
  // ws layout (bytes), total 417,333,248 < proven 425,721,856:
  char* p = (char*)d_ws;
  ushort_t* xk   = (ushort_t*)(p);                               //  67,108,864 (-> y)
  ushort_t* xv   = (ushort_t*)(p +  67108864);                   //  67,108,864
  ushort_t* xr   = (ushort_t*)(p + 134217728);                   //  67,108,864
  __half*   kbuf = (__half*)  (p + 201326592);                   //  67,108,864
  __half*   vbuf = (__half*)  (p + 268435456);                   //  67,108,864
  __half*   rbuf = (__half*)  (p + 335544320);                   //  67,108,864
  ushort_t* Wsp  = (ushort_t*)(p + 402653184);                   //   8,388,608 (4 bufs)
  float*    SA   = (float*)   (p + 411041792);                   //   2,097,152
  float*    SB   = (float*)   (p + 413138944);
  float*    SP   = (float*)   (p + 415236096);

  dim3 blk(256);
  const dim3 gblk(512);
  const unsigned lerpg = (unsigned)(nbt / 4 / 256);

  split_w<<<dim3(4 * CC * CC / 256), blk, 0, stream>>>(Wk, Wv, Wr, Wo, Wsp);
  lerp3<<<dim3(lerpg), blk, 0, stream>>>(x, mk, mv, mr, xk, xv, xr);

  // k,v,r GEMMs in one z-batched dispatch
  gemm_f16<1><<<dim3(512, 1, 3), gblk, 0, stream>>>(xk, Wsp, (void*)kbuf);

  const int nscan = BH * NCH * CC;
  wkv_phase_a<<<dim3(nscan / 256), blk, 0, stream>>>(kbuf, vbuf, decay, SA, SB, SP);
  wkv_combine<<<dim3(BH * CC / 256), blk, 0, stream>>>(SA, SB, SP, decay);
  wkv_phase_c<<<dim3(nscan / 256), blk, 0, stream>>>(kbuf, vbuf, rbuf, decay, first,
                                                     SA, SB, SP, xk);

  gemm_f16<0><<<dim3(512, 1, 1), gblk, 0, stream>>>(xk, Wsp + 3 * WS, (void*)out);
}